// Round 1
// 246.557 us; speedup vs baseline: 1.2111x; 1.2111x over previous
//
#include <hip/hip_runtime.h>
#include <math.h>

#define NN   5000
#define DEG  16
#define S    17
#define T    10
#define MN   10
#define D    128
#define NOUT 3
#define NSK  5

#define WPB   2            // waves per block = templates per block (main)
#define BLOCK (WPB * 64)
#define NEG   -3.0e38f

__device__ __forceinline__ float fast_rcp(float x) { return __builtin_amdgcn_rcpf(x); }

// DPP row_ror:k — pure-VALU cross-lane within each 16-lane row (~2cyc vs
// ds_bpermute's LDS-pipe ~35cyc latency).
template <int CTRL>
__device__ __forceinline__ float dpp_movf(float v) {
    return __int_as_float(__builtin_amdgcn_update_dpp(
        0, __float_as_int(v), CTRL, 0xF, 0xF, true));
}
__device__ __forceinline__ int dpp_movi(int v) {
    return __builtin_amdgcn_update_dpp(0, v, 0x121, 0xF, 0xF, true);
}
__device__ __forceinline__ float rowsum16(float v) {
    v += dpp_movf<0x121>(v);
    v += dpp_movf<0x122>(v);
    v += dpp_movf<0x124>(v);
    v += dpp_movf<0x128>(v);
    return v;
}
__device__ __forceinline__ float rowmax16(float v) {
    v = fmaxf(v, dpp_movf<0x121>(v));
    v = fmaxf(v, dpp_movf<0x122>(v));
    v = fmaxf(v, dpp_movf<0x124>(v));
    v = fmaxf(v, dpp_movf<0x128>(v));
    return v;
}

// ---------------- Pre-kernel: batch the per-node redundant work ----------------
// (unchanged from round 8) Mp[n,c] = xsq[n] - 2*(x[n].F2f[c]); masks[n][s];
// sqF2[100]. Main kernel gathers 5 floats + 5 masks from L2-resident ws.
__global__ __launch_bounds__(320) void ltfgw_pre(
    const float* __restrict__ x,        // [N, D]
    const int*   __restrict__ edge,     // [2, N*DEG]
    const float* __restrict__ F2,       // [T, MN, D] == [100, D] flat
    float*       __restrict__ wsMp,     // [N, 100]  xsq[n] - 2*dot
    unsigned*    __restrict__ wsMask,   // [N, 17]   adjacency bitmasks
    float*       __restrict__ wsSqF2)   // [100]
{
    const int n   = blockIdx.x;
    const int tid = threadIdx.x;
    const int* dst = edge + NN * DEG;

    if (n == NN) {                       // sqF2[c] = ||F2f[c]||^2
        if (tid < T * MN) {
            const float4* fr = (const float4*)(F2 + (size_t)tid * D);
            float acc = 0.f;
            #pragma unroll 8
            for (int i = 0; i < D / 4; ++i) {
                float4 f = fr[i];
                acc += f.x*f.x + f.y*f.y + f.z*f.z + f.w*f.w;
            }
            wsSqF2[tid] = acc;
        }
        return;
    }

    __shared__ int      loc[S];
    __shared__ int      neigh[S][DEG];
    __shared__ unsigned cm[S];
    __shared__ float    xsq_s;

    if (tid < S) { loc[tid] = (tid == 0) ? n : dst[n * DEG + tid - 1]; cm[tid] = 0u; }
    __syncthreads();

    if (tid < S * DEG) neigh[tid >> 4][tid & 15] = dst[loc[tid >> 4] * DEG + (tid & 15)];
    if (tid < 64) {                      // xsq[n] via wave-0 DPP reduce
        float v0 = x[(size_t)n * D + tid];
        float v1 = x[(size_t)n * D + 64 + tid];
        float pp = v0 * v0 + v1 * v1;
        pp = rowsum16(pp);
        pp += __shfl_xor(pp, 16, 64);
        pp += __shfl_xor(pp, 32, 64);
        if (tid == 0) xsq_s = pp;
    }
    __syncthreads();

    if (tid < S * S) {
        int a = tid / S, b = tid % S;
        int la = loc[a], lb = loc[b];
        bool adj = false;
        #pragma unroll
        for (int k = 0; k < DEG; ++k) adj = adj | (neigh[a][k] == lb) | (neigh[b][k] == la);
        if (a != b && adj) atomicOr(&cm[a], 1u << b);
    }
    __syncthreads();

    if (tid < S) wsMask[n * S + tid] = cm[tid];
    if (tid >= 32 && tid < 32 + T * MN) {  // Mp[n,c] = xsq - 2*(x[n].F2f[c])
        int c = tid - 32;
        const float4* fr = (const float4*)(F2 + (size_t)c * D);
        const float4* xr = (const float4*)(x + (size_t)n * D);
        float dotv = 0.f;
        #pragma unroll 8
        for (int d4 = 0; d4 < D / 4; ++d4) {
            float4 f = fr[d4], xv = xr[d4];
            dotv += f.x*xv.x + f.y*xv.y + f.z*xv.z + f.w*xv.w;
        }
        wsMp[n * (T * MN) + c] = xsq_s - 2.f * dotv;
    }
}

// ---------------- Main: one wave = one (node, template) OT problem ----------------
// Lane = q*16+m; lane owns rows s = q+4r (r=0..3) + row 16 (replicated
// across quads, counted once). All width-16 reductions via DPP.
// Round-9 change: tens = C1·H via the EXACT star structure of C1.
// From the pre-kernel mask semantics: msk[row 0] == 0x1FFFE for every node
// (center adjacent to all 16 neighbors), and bit 0 is set in every row s>=1
// (each neighbor is adjacent to the center). Neighbor-neighbor edges are
// rare (P ~ 2*DEG/N ~ 0.64% per pair). So:
//   tens[0]   = F - H[0]          (F = full column sum, cheap DPP/xor reduce)
//   tens[s>0] = H[0] + sum over extra bits of (msk & 0x1FFFE)
// H goes to LDS (conflict-free rows of 16) so the rare extras are gathered
// with broadcast ds_reads; this deletes the 16 bpermutes + 85 gated adds
// (~340 VALU/outer) of round 8. Sum-order change is ~1e-6 relative on tens.
// __launch_bounds__: block size ONLY (rounds 2-3: min-waves hint => spills).
__global__ __launch_bounds__(BLOCK) void ltfgw_wave(
    const int*      __restrict__ edge,     // [2, N*DEG]
    const float*    __restrict__ tmpl,     // [T, MN, MN]
    const float*    __restrict__ q0,       // [T, MN]
    const float*    __restrict__ alpha0,   // [1]
    const float*    __restrict__ wsMp,     // [N, 100]
    const unsigned* __restrict__ wsMask,   // [N, 17]
    const float*    __restrict__ wsSqF2,   // [100]
    float*          __restrict__ out)      // [N, T]
{
    const int blk  = blockIdx.x;
    const int n    = blk / 5;
    const int tp   = blk % 5;
    const int tid  = threadIdx.x;
    const int w    = tid >> 6;
    const int t    = tp * 2 + w;
    const int lane = tid & 63;
    const int q    = lane >> 4;
    const int m    = lane & 15;
    const bool act = (m < MN);
    const int mc   = act ? m : (MN - 1);

    __shared__ float C2l[WPB][MN][17];     // stride 17: conflict-free
    __shared__ float HL[WPB][18][16];      // H rows (17) + dump row; stride 16

    const int* dst = edge + NN * DEG;

    // q = softmax(q0[t]) via DPP row reduction (all lanes)
    float vq = q0[t * MN + mc];
    float zq = act ? vq : NEG;
    float mq = rowmax16(zq);
    float sq = rowsum16(__expf(zq - mq));     // inactive: exp(NEG-mq)=0
    const float qm = __expf(vq - (mq + __logf(sq)));   // valid on act lanes
    // C2 = softmax(tmpl, axis=1): active lane m of quad 0 does column m
    if (act && q == 0) {
        float v[MN]; float cm = NEG;
        #pragma unroll
        for (int i = 0; i < MN; ++i) { v[i] = tmpl[t * MN * MN + i * MN + m]; cm = fmaxf(cm, v[i]); }
        float ssum = 0.f;
        #pragma unroll
        for (int i = 0; i < MN; ++i) { v[i] = __expf(v[i] - cm); ssum += v[i]; }
        float inv = 1.f / ssum;
        #pragma unroll
        for (int i = 0; i < MN; ++i) C2l[w][i][m] = v[i] * inv;
    }

    // per-row gathers (L1/L2-resident ws): rows sr[r] = q+4r, clamp 16
    int sr[5];
    #pragma unroll
    for (int r = 0; r < 5; ++r) { int s0 = q + 4 * r; sr[r] = (s0 > 16) ? 16 : s0; }
    unsigned msk[5]; float npop[5]; float Mp[5];
    const int cidx = t * MN + mc;
    #pragma unroll
    for (int r = 0; r < 5; ++r) {
        int lr  = (sr[r] == 0) ? n : dst[n * DEG + sr[r] - 1];
        msk[r]  = wsMask[n * S + sr[r]];
        npop[r] = (float)__popc(msk[r]);
        Mp[r]   = wsMp[lr * (T * MN) + cidx];
    }
    const float sqf2c = wsSqF2[cidx];

    __syncthreads();   // C2l ready

    // C2rot[i] = C2[mc][sigma^i(m)] — sigma probed with the same DPP op,
    // so the rotated-G dot product below is rotation-direction-proof.
    float C2rot[16];
    {
        int li = m;
        #pragma unroll
        for (int i = 0; i < 16; ++i) {
            C2rot[i] = (li < MN) ? C2l[w][mc][li] : 0.f;
            if (i < 15) li = dpp_movi(li);
        }
    }
    // hC2 = sum_j C2[mc][j]^2 q[j]; qC2m = sum_j C2[mc][j] q[j]
    float hC2 = 0.f, qC2m = 0.f;
    {
        float qrot = qm;
        #pragma unroll
        for (int i = 0; i < 16; ++i) {
            float cq = C2rot[i] * qrot;
            qC2m += cq;
            hC2  = fmaf(C2rot[i], cq, hC2);
            if (i < 15) qrot = dpp_movf<0x121>(qrot);
        }
    }

    const float alpha = 1.f / (1.f + __expf(-alpha0[0]));
    const float oma   = 1.f - alpha;
    const float p_    = 1.f / (float)S;
    const float fa4   = 40.f * alpha;         // logK = lkP + 40*alpha*tens
    const float qop   = qm * (float)S;        // q/p for folded v-update
    const unsigned exm = act ? 0x1FFFEu : 0u; // extras mask (skip bit 0; gate act)
    const int j16  = (q == 0) ? 16 : 17;      // row-16 H write: q>0 -> dump row

    float lkP[5];
    #pragma unroll
    for (int r = 0; r < 5; ++r) {
        float M_ = Mp[r] + sqf2c;             // xsq + sqf2 - 2*dot
        float cC = npop[r] * p_ + hC2;        // hC1 = popc/S
        lkP[r] = -10.f * (oma * M_ + 2.f * alpha * cC);
    }

    // outer 0 analytic: G0 = p q^T => tens0[r] = p * qC2m * popc(msk[r])
    float tens[5], Kt[5], ub[5], v_, G[5];
    {
        float pq = p_ * qC2m;
        #pragma unroll
        for (int r = 0; r < 5; ++r) tens[r] = pq * npop[r];
    }

    for (int o = 1; o <= NOUT; ++o) {
        // K~ = exp(logK - rowmax) (rowmax via DPP)
        #pragma unroll
        for (int r = 0; r < 5; ++r) {
            float lk = fmaf(fa4, tens[r], lkP[r]);
            float rm = rowmax16(act ? lk : NEG);
            Kt[r] = act ? __expf(lk - rm) : 0.f;
        }
        float Kt4c = (q == 0) ? Kt[4] : 0.f;   // row 16 counted once in cs
        // folded exp-domain Sinkhorn: û = rcp(K~ v); v = (Sq)*rcp(K~^T û)
        v_ = act ? 1.f : 0.f;
        #pragma unroll
        for (int it = 0; it < NSK; ++it) {
            #pragma unroll
            for (int r = 0; r < 5; ++r)
                ub[r] = fast_rcp(rowsum16(Kt[r] * v_));
            float cs = Kt[0]*ub[0] + Kt[1]*ub[1] + Kt[2]*ub[2] + Kt[3]*ub[3]
                     + Kt4c*ub[4];
            cs += __shfl_xor(cs, 16, 64);
            cs += __shfl_xor(cs, 32, 64);
            v_ = act ? (qop * fast_rcp(cs)) : 0.f; // mask: rcp(0)=inf -> NaN
        }
        float pv = p_ * v_;
        #pragma unroll
        for (int r = 0; r < 5; ++r) G[r] = Kt[r] * ub[r] * pv;

        // H[own rows][m] = sum_k G[s][k]*C2[m][k] via DPP rotation (VALU-only)
        float H[5];
        #pragma unroll
        for (int r = 0; r < 5; ++r) {
            float h = 0.f, Gr = G[r];
            #pragma unroll
            for (int i = 0; i < 16; ++i) {
                h = fmaf(Gr, C2rot[i], h);
                if (i < 15) Gr = dpp_movf<0x121>(Gr);
            }
            H[r] = h;
        }

        // ---- tens = C1·H via exact star decomposition ----
        #pragma unroll
        for (int r = 0; r < 4; ++r) HL[w][q + 4*r][m] = H[r];  // rows 0..15
        HL[w][j16][m] = H[4];                                   // row 16 (q0)
        // F = sum_j H[j][m] (row 16 counted once)
        float Fs = H[0] + H[1] + H[2] + H[3] + ((q == 0) ? H[4] : 0.f);
        Fs += __shfl_xor(Fs, 16, 64);
        Fs += __shfl_xor(Fs, 32, 64);
        float h0 = HL[w][0][m];            // broadcast read, conflict-free
        #pragma unroll
        for (int r = 0; r < 5; ++r) {
            unsigned ex = msk[r] & exm;    // extras: bits 1..16
            if (r == 0) ex = (q == 0) ? 0u : ex;   // row 0 handled via Fs
            float tn = h0;                 // bit 0 always set for s>=1
            while (ex) {
                int j = __builtin_ctz(ex);
                ex &= ex - 1u;
                tn += HL[w][j][m];
            }
            tens[r] = tn;
        }
        if (q == 0) tens[0] = Fs - h0;     // row 0: all bits 1..16 set
    }

    // dist = sum G * (-0.1*lkP - a*cC - 2a*tens)
    float val = 0.f;
    #pragma unroll
    for (int r = 0; r < 5; ++r) {
        float cC = npop[r] * p_ + hC2;
        float integ = -0.1f * lkP[r] - alpha * cC - 2.f * alpha * tens[r];
        bool valid = act && (r < 4 || q == 0);
        val += valid ? G[r] * integ : 0.f;
    }
    val = rowsum16(val);
    val += __shfl_xor(val, 16, 64);
    val += __shfl_xor(val, 32, 64);
    if (lane == 0) out[n * T + t] = val;
}

extern "C" void kernel_launch(void* const* d_in, const int* in_sizes, int n_in,
                              void* d_out, int out_size, void* d_ws, size_t ws_size,
                              hipStream_t stream) {
    const float* x      = (const float*)d_in[0];
    const int*   edge   = (const int*)  d_in[1];
    const float* tmpl   = (const float*)d_in[2];
    const float* F2     = (const float*)d_in[3];
    const float* q0     = (const float*)d_in[4];
    const float* alpha0 = (const float*)d_in[5];
    float*       out    = (float*)d_out;

    // ws layout: Mp [N*100] f32 | masks [N*17] u32 | sqF2 [100] f32  (~2.34 MB)
    float*    wsMp    = (float*)d_ws;
    unsigned* wsMask  = (unsigned*)((char*)d_ws + (size_t)NN * T * MN * 4);
    float*    wsSqF2  = (float*)((char*)d_ws + (size_t)NN * T * MN * 4 + (size_t)NN * S * 4);

    hipLaunchKernelGGL(ltfgw_pre, dim3(NN + 1), dim3(320), 0, stream,
                       x, edge, F2, wsMp, wsMask, wsSqF2);
    hipLaunchKernelGGL(ltfgw_wave, dim3(NN * 5), dim3(BLOCK), 0, stream,
                       edge, tmpl, q0, alpha0, wsMp, wsMask, wsSqF2, out);
}

// Round 2
// 236.026 us; speedup vs baseline: 1.2651x; 1.0446x over previous
//
#include <hip/hip_runtime.h>
#include <math.h>

#define NN   5000
#define DEG  16
#define S    17
#define T    10
#define MN   10
#define D    128
#define NOUT 3
#define NSK  5

#define WPB   2            // waves per block = templates per block (main)
#define BLOCK (WPB * 64)
#define NEG   -3.0e38f
#define LOG2E 1.44269504088896f
#define LN2   0.69314718055995f

typedef unsigned uint2v __attribute__((ext_vector_type(2)));

__device__ __forceinline__ float fast_rcp(float x) { return __builtin_amdgcn_rcpf(x); }

#if __has_builtin(__builtin_amdgcn_exp2f)
__device__ __forceinline__ float fast_exp2(float x) { return __builtin_amdgcn_exp2f(x); }
#else
__device__ __forceinline__ float fast_exp2(float x) { return __expf(x * LN2); }
#endif

// DPP row_ror:k — pure-VALU cross-lane within each 16-lane row.
template <int CTRL>
__device__ __forceinline__ float dpp_movf(float v) {
    return __int_as_float(__builtin_amdgcn_update_dpp(
        0, __float_as_int(v), CTRL, 0xF, 0xF, true));
}
__device__ __forceinline__ int dpp_movi(int v) {
    return __builtin_amdgcn_update_dpp(0, v, 0x121, 0xF, 0xF, true);
}
__device__ __forceinline__ float rowsum16(float v) {
    v += dpp_movf<0x121>(v);
    v += dpp_movf<0x122>(v);
    v += dpp_movf<0x124>(v);
    v += dpp_movf<0x128>(v);
    return v;
}
__device__ __forceinline__ float rowmax16(float v) {
    v = fmaxf(v, dpp_movf<0x121>(v));
    v = fmaxf(v, dpp_movf<0x122>(v));
    v = fmaxf(v, dpp_movf<0x124>(v));
    v = fmaxf(v, dpp_movf<0x128>(v));
    return v;
}

// gfx950 permlane-swap butterflies: v + v[lane^16] / v[lane^32] in pure VALU
// (replaces ds_bpermute round trips on the Sinkhorn critical path).
// Self-swap a=b=v then a+b is direction-proof regardless of swap orientation.
__device__ __forceinline__ float bfly16(float v) {
#if __has_builtin(__builtin_amdgcn_permlane16_swap)
    uint2v r = __builtin_amdgcn_permlane16_swap(__float_as_uint(v), __float_as_uint(v),
                                                false, false);
    return __uint_as_float(r[0]) + __uint_as_float(r[1]);
#else
    // ds_swizzle xor-16 within each 32-lane group (BitMode: xor=0x10, and=0x1F)
    return v + __int_as_float(__builtin_amdgcn_ds_swizzle(__float_as_int(v), 0x401F));
#endif
}
__device__ __forceinline__ float bfly32(float v) {
#if __has_builtin(__builtin_amdgcn_permlane32_swap)
    uint2v r = __builtin_amdgcn_permlane32_swap(__float_as_uint(v), __float_as_uint(v),
                                                false, false);
    return __uint_as_float(r[0]) + __uint_as_float(r[1]);
#else
    return v + __shfl_xor(v, 32, 64);
#endif
}

// ---------------- Pre-kernel: batch the per-node redundant work ----------------
// (unchanged) Mp[n,c] = xsq[n] - 2*(x[n].F2f[c]); masks[n][s]; sqF2[100].
__global__ __launch_bounds__(320) void ltfgw_pre(
    const float* __restrict__ x,        // [N, D]
    const int*   __restrict__ edge,     // [2, N*DEG]
    const float* __restrict__ F2,       // [T, MN, D] == [100, D] flat
    float*       __restrict__ wsMp,     // [N, 100]  xsq[n] - 2*dot
    unsigned*    __restrict__ wsMask,   // [N, 17]   adjacency bitmasks
    float*       __restrict__ wsSqF2)   // [100]
{
    const int n   = blockIdx.x;
    const int tid = threadIdx.x;
    const int* dst = edge + NN * DEG;

    if (n == NN) {                       // sqF2[c] = ||F2f[c]||^2
        if (tid < T * MN) {
            const float4* fr = (const float4*)(F2 + (size_t)tid * D);
            float acc = 0.f;
            #pragma unroll 8
            for (int i = 0; i < D / 4; ++i) {
                float4 f = fr[i];
                acc += f.x*f.x + f.y*f.y + f.z*f.z + f.w*f.w;
            }
            wsSqF2[tid] = acc;
        }
        return;
    }

    __shared__ int      loc[S];
    __shared__ int      neigh[S][DEG];
    __shared__ unsigned cm[S];
    __shared__ float    xsq_s;

    if (tid < S) { loc[tid] = (tid == 0) ? n : dst[n * DEG + tid - 1]; cm[tid] = 0u; }
    __syncthreads();

    if (tid < S * DEG) neigh[tid >> 4][tid & 15] = dst[loc[tid >> 4] * DEG + (tid & 15)];
    if (tid < 64) {                      // xsq[n] via wave-0 DPP reduce
        float v0 = x[(size_t)n * D + tid];
        float v1 = x[(size_t)n * D + 64 + tid];
        float pp = v0 * v0 + v1 * v1;
        pp = rowsum16(pp);
        pp += __shfl_xor(pp, 16, 64);
        pp += __shfl_xor(pp, 32, 64);
        if (tid == 0) xsq_s = pp;
    }
    __syncthreads();

    if (tid < S * S) {
        int a = tid / S, b = tid % S;
        int la = loc[a], lb = loc[b];
        bool adj = false;
        #pragma unroll
        for (int k = 0; k < DEG; ++k) adj = adj | (neigh[a][k] == lb) | (neigh[b][k] == la);
        if (a != b && adj) atomicOr(&cm[a], 1u << b);
    }
    __syncthreads();

    if (tid < S) wsMask[n * S + tid] = cm[tid];
    if (tid >= 32 && tid < 32 + T * MN) {  // Mp[n,c] = xsq - 2*(x[n].F2f[c])
        int c = tid - 32;
        const float4* fr = (const float4*)(F2 + (size_t)c * D);
        const float4* xr = (const float4*)(x + (size_t)n * D);
        float dotv = 0.f;
        #pragma unroll 8
        for (int d4 = 0; d4 < D / 4; ++d4) {
            float4 f = fr[d4], xv = xr[d4];
            dotv += f.x*xv.x + f.y*xv.y + f.z*xv.z + f.w*xv.w;
        }
        wsMp[n * (T * MN) + c] = xsq_s - 2.f * dotv;
    }
}

// ---------------- Main: one wave = one (node, template) OT problem ----------------
// Lane = q*16+m; lane owns rows s = q+4r (r=0..3) + row 16 (replicated, counted
// once). Round-10 changes:
//  (a) permlane16/32_swap butterflies replace all __shfl_xor (ds_bpermute) —
//      30 LDS round-trips removed from the Sinkhorn critical path.
//  (b) Kt rowmax hoisted out of the outer loop: Sinkhorn is invariant to any
//      per-row K scale, so rm = rowmax(lkP)+14.4 precomputed once suffices
//      (lk - rm <= 40a*tens*log2e - 14.4, tens<=~1 since G rows sum to p).
//  (c) exp2 domain: ln2 folded into lkP2/fa42 constants (v_exp_f32 is exp2).
//  (d) tens = C1*(G*C2^T) via k-domain star decomposition: colG[k]=sum_j G[j][k]
//      (butterfly) then TWO rotations (F from colG, H0 from LDS-broadcast G row
//      0) instead of five; rare extras recomputed as 10-term LDS dots.
// __launch_bounds__: block size ONLY (rounds 2-3: min-waves hint => spills).
__global__ __launch_bounds__(BLOCK) void ltfgw_wave(
    const int*      __restrict__ edge,     // [2, N*DEG]
    const float*    __restrict__ tmpl,     // [T, MN, MN]
    const float*    __restrict__ q0,       // [T, MN]
    const float*    __restrict__ alpha0,   // [1]
    const float*    __restrict__ wsMp,     // [N, 100]
    const unsigned* __restrict__ wsMask,   // [N, 17]
    const float*    __restrict__ wsSqF2,   // [100]
    float*          __restrict__ out)      // [N, T]
{
    const int blk  = blockIdx.x;
    const int n    = blk / 5;
    const int tp   = blk % 5;
    const int tid  = threadIdx.x;
    const int w    = tid >> 6;
    const int t    = tp * 2 + w;
    const int lane = tid & 63;
    const int q    = lane >> 4;
    const int m    = lane & 15;
    const bool act = (m < MN);
    const int mc   = act ? m : (MN - 1);

    __shared__ float C2l[WPB][MN][17];     // stride 17: conflict-free
    __shared__ float GL[WPB][18][16];      // G rows (17) + dump row; stride 16

    const int* dst = edge + NN * DEG;

    // q = softmax(q0[t]) via DPP row reduction (all lanes)
    float vq = q0[t * MN + mc];
    float zq = act ? vq : NEG;
    float mq = rowmax16(zq);
    float sq = rowsum16(__expf(zq - mq));     // inactive: exp(NEG-mq)=0
    const float qm = __expf(vq - (mq + __logf(sq)));   // valid on act lanes
    // C2 = softmax(tmpl, axis=1): active lane m of quad 0 does column m
    if (act && q == 0) {
        float v[MN]; float cmx = NEG;
        #pragma unroll
        for (int i = 0; i < MN; ++i) { v[i] = tmpl[t * MN * MN + i * MN + m]; cmx = fmaxf(cmx, v[i]); }
        float ssum = 0.f;
        #pragma unroll
        for (int i = 0; i < MN; ++i) { v[i] = __expf(v[i] - cmx); ssum += v[i]; }
        float inv = 1.f / ssum;
        #pragma unroll
        for (int i = 0; i < MN; ++i) C2l[w][i][m] = v[i] * inv;
    }

    // per-row gathers (L1/L2-resident ws): rows sr[r] = q+4r, clamp 16
    int sr[5];
    #pragma unroll
    for (int r = 0; r < 5; ++r) { int s0 = q + 4 * r; sr[r] = (s0 > 16) ? 16 : s0; }
    unsigned msk[5]; float npop[5]; float Mp[5];
    const int cidx = t * MN + mc;
    #pragma unroll
    for (int r = 0; r < 5; ++r) {
        int lr  = (sr[r] == 0) ? n : dst[n * DEG + sr[r] - 1];
        msk[r]  = wsMask[n * S + sr[r]];
        npop[r] = (float)__popc(msk[r]);
        Mp[r]   = wsMp[lr * (T * MN) + cidx];
    }
    const float sqf2c = wsSqF2[cidx];

    __syncthreads();   // C2l ready

    // C2rot[i] = C2[mc][sigma^i(m)] — sigma probed with the same DPP op,
    // so the rotated dot products below are rotation-direction-proof.
    float C2rot[16];
    {
        int li = m;
        #pragma unroll
        for (int i = 0; i < 16; ++i) {
            C2rot[i] = (li < MN) ? C2l[w][mc][li] : 0.f;
            if (i < 15) li = dpp_movi(li);
        }
    }
    // hC2 = sum_j C2[mc][j]^2 q[j]; qC2m = sum_j C2[mc][j] q[j]
    float hC2 = 0.f, qC2m = 0.f;
    {
        float qrot = qm;
        #pragma unroll
        for (int i = 0; i < 16; ++i) {
            float cq = C2rot[i] * qrot;
            qC2m += cq;
            hC2  = fmaf(C2rot[i], cq, hC2);
            if (i < 15) qrot = dpp_movf<0x121>(qrot);
        }
    }

    const float alpha = 1.f / (1.f + __expf(-alpha0[0]));
    const float oma   = 1.f - alpha;
    const float p_    = 1.f / (float)S;
    const float fa42  = 40.f * alpha * LOG2E; // log2K = lkP2 + fa42*tens
    const float qop   = qm * (float)S;        // q/p for folded v-update
    const unsigned exm = act ? 0x1FFFEu : 0u; // extras mask (skip bit 0; gate act)
    const int j16  = (q == 0) ? 16 : 17;      // row-16 G write: q>0 -> dump row

    // lkP2b = log2-domain linear part, pre-shifted by hoisted row stabilizer.
    float lkP2b[5], rm2[5];
    {
        const float nl2e10 = -10.f * LOG2E;
        #pragma unroll
        for (int r = 0; r < 5; ++r) {
            float M_ = Mp[r] + sqf2c;             // xsq + sqf2 - 2*dot
            float cC = npop[r] * p_ + hC2;        // hC1 = popc/S
            float lk2 = nl2e10 * (oma * M_ + 2.f * alpha * cC);
            rm2[r]   = rowmax16(act ? lk2 : NEG) + 14.4f;  // bias: overflow headroom
            lkP2b[r] = lk2 - rm2[r];
        }
    }

    // outer 0 analytic: G0 = p q^T => tens0[r] = p * qC2m * popc(msk[r])
    float tens[5], Kt[5], ub[5], v_, G[5];
    {
        float pq = p_ * qC2m;
        #pragma unroll
        for (int r = 0; r < 5; ++r) tens[r] = pq * npop[r];
    }

    for (int o = 1; o <= NOUT; ++o) {
        // K~ = exp2(lkP2b + fa42*tens)  (rowmax hoisted; Sinkhorn scale-invariant)
        #pragma unroll
        for (int r = 0; r < 5; ++r)
            Kt[r] = act ? fast_exp2(fmaf(fa42, tens[r], lkP2b[r])) : 0.f;
        float Kt4c = (q == 0) ? Kt[4] : 0.f;   // row 16 counted once in cs

        // folded exp-domain Sinkhorn: û = rcp(K~ v); v = (Sq)*rcp(K~^T û)
        // iter 0 peeled (v == 1)
        #pragma unroll
        for (int r = 0; r < 5; ++r) ub[r] = fast_rcp(rowsum16(Kt[r]));
        {
            float cs = Kt[0] * ub[0];
            cs = fmaf(Kt[1], ub[1], cs);
            cs = fmaf(Kt[2], ub[2], cs);
            cs = fmaf(Kt[3], ub[3], cs);
            cs = fmaf(Kt4c,  ub[4], cs);
            cs = bfly16(cs); cs = bfly32(cs);
            v_ = act ? (qop * fast_rcp(cs)) : 0.f; // mask: rcp(0)=inf -> NaN
        }
        #pragma unroll
        for (int it = 1; it < NSK; ++it) {
            #pragma unroll
            for (int r = 0; r < 5; ++r)
                ub[r] = fast_rcp(rowsum16(Kt[r] * v_));
            float cs = Kt[0] * ub[0];
            cs = fmaf(Kt[1], ub[1], cs);
            cs = fmaf(Kt[2], ub[2], cs);
            cs = fmaf(Kt[3], ub[3], cs);
            cs = fmaf(Kt4c,  ub[4], cs);
            cs = bfly16(cs); cs = bfly32(cs);
            v_ = act ? (qop * fast_rcp(cs)) : 0.f;
        }
        float pv = p_ * v_;
        #pragma unroll
        for (int r = 0; r < 5; ++r) G[r] = Kt[r] * ub[r] * pv;

        // ---- tens = C1*(G*C2^T), star-decomposed in the k-domain ----
        #pragma unroll
        for (int r = 0; r < 4; ++r) GL[w][q + 4*r][m] = G[r];   // rows 0..15
        GL[w][j16][m] = G[4];                                    // row 16 (q0)
        // colG[k] = sum_j G[j][k]  (row 16 counted once)
        float cg = G[0] + G[1] + G[2] + G[3] + ((q == 0) ? G[4] : 0.f);
        cg = bfly16(cg); cg = bfly32(cg);
        float g0 = GL[w][0][m];            // broadcast read of G row 0
        // F[m] = sum_k colG[k]*C2[m][k]; H0[m] = sum_k G[0][k]*C2[m][k]
        float Fm = 0.f, H0 = 0.f;
        #pragma unroll
        for (int i = 0; i < 16; ++i) {
            Fm = fmaf(cg, C2rot[i], Fm);
            H0 = fmaf(g0, C2rot[i], H0);
            if (i < 15) { cg = dpp_movf<0x121>(cg); g0 = dpp_movf<0x121>(g0); }
        }
        // tens[0] = F - H0 (row 0: all bits 1..16 set);
        // tens[s>=1] = H0 + sum over rare extra bits of H[j][m], recomputed as
        // 10-term LDS dots (j uniform per quad -> broadcast, conflict-free).
        #pragma unroll
        for (int r = 0; r < 5; ++r) {
            unsigned ex = msk[r] & exm;    // extras: bits 1..16
            if (r == 0) ex = (q == 0) ? 0u : ex;   // row 0 handled via Fm
            float tn = H0;                 // bit 0 always set for s>=1
            while (ex) {
                int j = __builtin_ctz(ex);
                ex &= ex - 1u;
                const float* gr = &GL[w][j][0];
                const float* cr = &C2l[w][mc][0];
                float e = 0.f;
                #pragma unroll
                for (int k = 0; k < MN; ++k) e = fmaf(gr[k], cr[k], e);
                tn += e;
            }
            tens[r] = tn;
        }
        if (q == 0) tens[0] = Fm - H0;
    }

    // dist = sum G * ((1-a)M + a*constC - 2a*tens); lk2 = lkP2b + rm2 (log2 units)
    float val = 0.f;
    #pragma unroll
    for (int r = 0; r < 5; ++r) {
        float cC = npop[r] * p_ + hC2;
        float lk2r = lkP2b[r] + rm2[r];
        float integ = -(0.1f * LN2) * lk2r - alpha * cC - 2.f * alpha * tens[r];
        bool valid = act && (r < 4 || q == 0);
        val += valid ? G[r] * integ : 0.f;
    }
    val = rowsum16(val);
    val = bfly16(val);
    val = bfly32(val);
    if (lane == 0) out[n * T + t] = val;
}

extern "C" void kernel_launch(void* const* d_in, const int* in_sizes, int n_in,
                              void* d_out, int out_size, void* d_ws, size_t ws_size,
                              hipStream_t stream) {
    const float* x      = (const float*)d_in[0];
    const int*   edge   = (const int*)  d_in[1];
    const float* tmpl   = (const float*)d_in[2];
    const float* F2     = (const float*)d_in[3];
    const float* q0     = (const float*)d_in[4];
    const float* alpha0 = (const float*)d_in[5];
    float*       out    = (float*)d_out;

    // ws layout: Mp [N*100] f32 | masks [N*17] u32 | sqF2 [100] f32  (~2.34 MB)
    float*    wsMp    = (float*)d_ws;
    unsigned* wsMask  = (unsigned*)((char*)d_ws + (size_t)NN * T * MN * 4);
    float*    wsSqF2  = (float*)((char*)d_ws + (size_t)NN * T * MN * 4 + (size_t)NN * S * 4);

    hipLaunchKernelGGL(ltfgw_pre, dim3(NN + 1), dim3(320), 0, stream,
                       x, edge, F2, wsMp, wsMask, wsSqF2);
    hipLaunchKernelGGL(ltfgw_wave, dim3(NN * 5), dim3(BLOCK), 0, stream,
                       edge, tmpl, q0, alpha0, wsMp, wsMask, wsSqF2, out);
}

// Round 3
// 234.976 us; speedup vs baseline: 1.2708x; 1.0045x over previous
//
#include <hip/hip_runtime.h>
#include <math.h>

#define NN   5000
#define DEG  16
#define S    17
#define T    10
#define MN   10
#define D    128
#define NOUT 3
#define NSK  5

#define WPB   8            // waves per block (wave-private work; no barrier)
#define BLOCK (WPB * 64)
#define NEG   -3.0e38f
#define LOG2E 1.44269504088896f
#define LN2   0.69314718055995f

typedef unsigned uint2v __attribute__((ext_vector_type(2)));

__device__ __forceinline__ float fast_rcp(float x) { return __builtin_amdgcn_rcpf(x); }

#if __has_builtin(__builtin_amdgcn_exp2f)
__device__ __forceinline__ float fast_exp2(float x) { return __builtin_amdgcn_exp2f(x); }
#else
__device__ __forceinline__ float fast_exp2(float x) { return __expf(x * LN2); }
#endif

// DPP row_ror:k — pure-VALU cross-lane within each 16-lane row.
template <int CTRL>
__device__ __forceinline__ float dpp_movf(float v) {
    return __int_as_float(__builtin_amdgcn_update_dpp(
        0, __float_as_int(v), CTRL, 0xF, 0xF, true));
}
__device__ __forceinline__ int dpp_movi(int v) {
    return __builtin_amdgcn_update_dpp(0, v, 0x121, 0xF, 0xF, true);
}
__device__ __forceinline__ float rowsum16(float v) {
    v += dpp_movf<0x121>(v);
    v += dpp_movf<0x122>(v);
    v += dpp_movf<0x124>(v);
    v += dpp_movf<0x128>(v);
    return v;
}
__device__ __forceinline__ float rowmax16(float v) {
    v = fmaxf(v, dpp_movf<0x121>(v));
    v = fmaxf(v, dpp_movf<0x122>(v));
    v = fmaxf(v, dpp_movf<0x124>(v));
    v = fmaxf(v, dpp_movf<0x128>(v));
    return v;
}

// gfx950 permlane-swap butterflies: v + v[lane^16] / v[lane^32] in pure VALU.
__device__ __forceinline__ float bfly16(float v) {
#if __has_builtin(__builtin_amdgcn_permlane16_swap)
    uint2v r = __builtin_amdgcn_permlane16_swap(__float_as_uint(v), __float_as_uint(v),
                                                false, false);
    return __uint_as_float(r[0]) + __uint_as_float(r[1]);
#else
    return v + __int_as_float(__builtin_amdgcn_ds_swizzle(__float_as_int(v), 0x401F));
#endif
}
__device__ __forceinline__ float bfly32(float v) {
#if __has_builtin(__builtin_amdgcn_permlane32_swap)
    uint2v r = __builtin_amdgcn_permlane32_swap(__float_as_uint(v), __float_as_uint(v),
                                                false, false);
    return __uint_as_float(r[0]) + __uint_as_float(r[1]);
#else
    return v + __shfl_xor(v, 32, 64);
#endif
}

// ---------------- Pre-kernel: batch the per-node redundant work ----------------
// (unchanged) Mp[n,c] = xsq[n] - 2*(x[n].F2f[c]); masks[n][s]; sqF2[100].
__global__ __launch_bounds__(320) void ltfgw_pre(
    const float* __restrict__ x,        // [N, D]
    const int*   __restrict__ edge,     // [2, N*DEG]
    const float* __restrict__ F2,       // [T, MN, D] == [100, D] flat
    float*       __restrict__ wsMp,     // [N, 100]  xsq[n] - 2*dot
    unsigned*    __restrict__ wsMask,   // [N, 17]   adjacency bitmasks
    float*       __restrict__ wsSqF2)   // [100]
{
    const int n   = blockIdx.x;
    const int tid = threadIdx.x;
    const int* dst = edge + NN * DEG;

    if (n == NN) {                       // sqF2[c] = ||F2f[c]||^2
        if (tid < T * MN) {
            const float4* fr = (const float4*)(F2 + (size_t)tid * D);
            float acc = 0.f;
            #pragma unroll 8
            for (int i = 0; i < D / 4; ++i) {
                float4 f = fr[i];
                acc += f.x*f.x + f.y*f.y + f.z*f.z + f.w*f.w;
            }
            wsSqF2[tid] = acc;
        }
        return;
    }

    __shared__ int      loc[S];
    __shared__ int      neigh[S][DEG];
    __shared__ unsigned cm[S];
    __shared__ float    xsq_s;

    if (tid < S) { loc[tid] = (tid == 0) ? n : dst[n * DEG + tid - 1]; cm[tid] = 0u; }
    __syncthreads();

    if (tid < S * DEG) neigh[tid >> 4][tid & 15] = dst[loc[tid >> 4] * DEG + (tid & 15)];
    if (tid < 64) {                      // xsq[n] via wave-0 DPP reduce
        float v0 = x[(size_t)n * D + tid];
        float v1 = x[(size_t)n * D + 64 + tid];
        float pp = v0 * v0 + v1 * v1;
        pp = rowsum16(pp);
        pp += __shfl_xor(pp, 16, 64);
        pp += __shfl_xor(pp, 32, 64);
        if (tid == 0) xsq_s = pp;
    }
    __syncthreads();

    if (tid < S * S) {
        int a = tid / S, b = tid % S;
        int la = loc[a], lb = loc[b];
        bool adj = false;
        #pragma unroll
        for (int k = 0; k < DEG; ++k) adj = adj | (neigh[a][k] == lb) | (neigh[b][k] == la);
        if (a != b && adj) atomicOr(&cm[a], 1u << b);
    }
    __syncthreads();

    if (tid < S) wsMask[n * S + tid] = cm[tid];
    if (tid >= 32 && tid < 32 + T * MN) {  // Mp[n,c] = xsq - 2*(x[n].F2f[c])
        int c = tid - 32;
        const float4* fr = (const float4*)(F2 + (size_t)c * D);
        const float4* xr = (const float4*)(x + (size_t)n * D);
        float dotv = 0.f;
        #pragma unroll 8
        for (int d4 = 0; d4 < D / 4; ++d4) {
            float4 f = fr[d4], xv = xr[d4];
            dotv += f.x*xv.x + f.y*xv.y + f.z*xv.z + f.w*xv.w;
        }
        wsMp[n * (T * MN) + c] = xsq_s - 2.f * dotv;
    }
}

// ---------------- Main: one wave = one (node, template) OT problem ----------------
// Round-11 change: occupancy. Three rounds of counters pinned OccupancyPercent
// at ~50% (16 waves/CU) regardless of VGPR (32-48) / LDS (1.5-4KB) — i.e. an
// ~8-workgroup/CU slot cap, not a resource cap. All LDS here (C2l[w], GL[w])
// is WAVE-private, so the old __syncthreads was vestigial: pack 8 independent
// waves per 512-thread block (4 blocks/CU = 32 waves = 100% static occupancy),
// no barrier at all. Same-wave LDS write->read is ordered by compiler lgkmcnt.
// Also: C2 row hoisted to registers (crReg) so the rare extras-dot stops
// re-reading C2l inside the divergent loop; fast_rcp for softmax/sigmoid
// denominators (kills two exact-division expansions).
// __launch_bounds__: block size ONLY (rounds 2-3: min-waves hint => spills).
__global__ __launch_bounds__(BLOCK) void ltfgw_wave(
    const int*      __restrict__ edge,     // [2, N*DEG]
    const float*    __restrict__ tmpl,     // [T, MN, MN]
    const float*    __restrict__ q0,       // [T, MN]
    const float*    __restrict__ alpha0,   // [1]
    const float*    __restrict__ wsMp,     // [N, 100]
    const unsigned* __restrict__ wsMask,   // [N, 17]
    const float*    __restrict__ wsSqF2,   // [100]
    float*          __restrict__ out)      // [N, T]
{
    const int tid  = threadIdx.x;
    const int w    = tid >> 6;
    const int gid  = blockIdx.x * WPB + w;   // flat (node, template) id
    const int n    = gid / T;
    const int t    = gid - n * T;
    const int lane = tid & 63;
    const int q    = lane >> 4;
    const int m    = lane & 15;
    const bool act = (m < MN);
    const int mc   = act ? m : (MN - 1);

    __shared__ float C2l[WPB][MN][17];     // wave-private; stride 17: conflict-free
    __shared__ float GL[WPB][18][16];      // wave-private; G rows (17) + dump row

    const int* dst = edge + NN * DEG;

    // q = softmax(q0[t]) via DPP row reduction (all lanes)
    float vq = q0[t * MN + mc];
    float zq = act ? vq : NEG;
    float mq = rowmax16(zq);
    float sq = rowsum16(__expf(zq - mq));     // inactive: exp(NEG-mq)=0
    const float qm = __expf(vq - (mq + __logf(sq)));   // valid on act lanes
    // C2 = softmax(tmpl, axis=1): active lane m of quad 0 does column m
    if (act && q == 0) {
        float v[MN]; float cmx = NEG;
        #pragma unroll
        for (int i = 0; i < MN; ++i) { v[i] = tmpl[t * MN * MN + i * MN + m]; cmx = fmaxf(cmx, v[i]); }
        float ssum = 0.f;
        #pragma unroll
        for (int i = 0; i < MN; ++i) { v[i] = __expf(v[i] - cmx); ssum += v[i]; }
        float inv = fast_rcp(ssum);
        #pragma unroll
        for (int i = 0; i < MN; ++i) C2l[w][i][m] = v[i] * inv;
    }

    // per-row gathers (L1/L2-resident ws): rows sr[r] = q+4r, clamp 16
    int sr[5];
    #pragma unroll
    for (int r = 0; r < 5; ++r) { int s0 = q + 4 * r; sr[r] = (s0 > 16) ? 16 : s0; }
    unsigned msk[5]; float npop[5]; float Mp[5];
    const int cidx = t * MN + mc;
    #pragma unroll
    for (int r = 0; r < 5; ++r) {
        int lr  = (sr[r] == 0) ? n : dst[n * DEG + sr[r] - 1];
        msk[r]  = wsMask[n * S + sr[r]];
        npop[r] = (float)__popc(msk[r]);
        Mp[r]   = wsMp[lr * (T * MN) + cidx];
    }
    const float sqf2c = wsSqF2[cidx];

    // C2 row mc in registers (same-wave LDS RAW: compiler inserts lgkmcnt)
    float crReg[MN];
    #pragma unroll
    for (int k = 0; k < MN; ++k) crReg[k] = C2l[w][mc][k];

    // C2rot[i] = C2[mc][sigma^i(m)] — sigma probed with the same DPP op,
    // so the rotated dot products below are rotation-direction-proof.
    float C2rot[16];
    {
        int li = m;
        #pragma unroll
        for (int i = 0; i < 16; ++i) {
            C2rot[i] = (li < MN) ? C2l[w][mc][li] : 0.f;
            if (i < 15) li = dpp_movi(li);
        }
    }
    // hC2 = sum_j C2[mc][j]^2 q[j]; qC2m = sum_j C2[mc][j] q[j]
    float hC2 = 0.f, qC2m = 0.f;
    {
        float qrot = qm;
        #pragma unroll
        for (int i = 0; i < 16; ++i) {
            float cq = C2rot[i] * qrot;
            qC2m += cq;
            hC2  = fmaf(C2rot[i], cq, hC2);
            if (i < 15) qrot = dpp_movf<0x121>(qrot);
        }
    }

    const float alpha = fast_rcp(1.f + __expf(-alpha0[0]));
    const float oma   = 1.f - alpha;
    const float p_    = 1.f / (float)S;
    const float fa42  = 40.f * alpha * LOG2E; // log2K = lkP2 + fa42*tens
    const float qop   = qm * (float)S;        // q/p for folded v-update
    const unsigned exm = act ? 0x1FFFEu : 0u; // extras mask (skip bit 0; gate act)
    const int j16  = (q == 0) ? 16 : 17;      // row-16 G write: q>0 -> dump row

    // lkP2b = log2-domain linear part, pre-shifted by hoisted row stabilizer.
    float lkP2b[5], rm2[5];
    {
        const float nl2e10 = -10.f * LOG2E;
        #pragma unroll
        for (int r = 0; r < 5; ++r) {
            float M_ = Mp[r] + sqf2c;             // xsq + sqf2 - 2*dot
            float cC = npop[r] * p_ + hC2;        // hC1 = popc/S
            float lk2 = nl2e10 * (oma * M_ + 2.f * alpha * cC);
            rm2[r]   = rowmax16(act ? lk2 : NEG) + 14.4f;  // bias: overflow headroom
            lkP2b[r] = lk2 - rm2[r];
        }
    }

    // outer 0 analytic: G0 = p q^T => tens0[r] = p * qC2m * popc(msk[r])
    float tens[5], Kt[5], ub[5], v_, G[5];
    {
        float pq = p_ * qC2m;
        #pragma unroll
        for (int r = 0; r < 5; ++r) tens[r] = pq * npop[r];
    }

    for (int o = 1; o <= NOUT; ++o) {
        // K~ = exp2(lkP2b + fa42*tens)  (rowmax hoisted; Sinkhorn scale-invariant)
        #pragma unroll
        for (int r = 0; r < 5; ++r)
            Kt[r] = act ? fast_exp2(fmaf(fa42, tens[r], lkP2b[r])) : 0.f;
        float Kt4c = (q == 0) ? Kt[4] : 0.f;   // row 16 counted once in cs

        // folded exp-domain Sinkhorn: û = rcp(K~ v); v = (Sq)*rcp(K~^T û)
        // iter 0 peeled (v == 1)
        #pragma unroll
        for (int r = 0; r < 5; ++r) ub[r] = fast_rcp(rowsum16(Kt[r]));
        {
            float cs = Kt[0] * ub[0];
            cs = fmaf(Kt[1], ub[1], cs);
            cs = fmaf(Kt[2], ub[2], cs);
            cs = fmaf(Kt[3], ub[3], cs);
            cs = fmaf(Kt4c,  ub[4], cs);
            cs = bfly16(cs); cs = bfly32(cs);
            v_ = act ? (qop * fast_rcp(cs)) : 0.f; // mask: rcp(0)=inf -> NaN
        }
        #pragma unroll
        for (int it = 1; it < NSK; ++it) {
            #pragma unroll
            for (int r = 0; r < 5; ++r)
                ub[r] = fast_rcp(rowsum16(Kt[r] * v_));
            float cs = Kt[0] * ub[0];
            cs = fmaf(Kt[1], ub[1], cs);
            cs = fmaf(Kt[2], ub[2], cs);
            cs = fmaf(Kt[3], ub[3], cs);
            cs = fmaf(Kt4c,  ub[4], cs);
            cs = bfly16(cs); cs = bfly32(cs);
            v_ = act ? (qop * fast_rcp(cs)) : 0.f;
        }
        float pv = p_ * v_;
        #pragma unroll
        for (int r = 0; r < 5; ++r) G[r] = Kt[r] * ub[r] * pv;

        // ---- tens = C1*(G*C2^T), star-decomposed in the k-domain ----
        #pragma unroll
        for (int r = 0; r < 4; ++r) GL[w][q + 4*r][m] = G[r];   // rows 0..15
        GL[w][j16][m] = G[4];                                    // row 16 (q0)
        // colG[k] = sum_j G[j][k]  (row 16 counted once)
        float cg = G[0] + G[1] + G[2] + G[3] + ((q == 0) ? G[4] : 0.f);
        cg = bfly16(cg); cg = bfly32(cg);
        float g0 = GL[w][0][m];            // broadcast read of G row 0
        // F[m] = sum_k colG[k]*C2[m][k]; H0[m] = sum_k G[0][k]*C2[m][k]
        float Fm = 0.f, H0 = 0.f;
        #pragma unroll
        for (int i = 0; i < 16; ++i) {
            Fm = fmaf(cg, C2rot[i], Fm);
            H0 = fmaf(g0, C2rot[i], H0);
            if (i < 15) { cg = dpp_movf<0x121>(cg); g0 = dpp_movf<0x121>(g0); }
        }
        // tens[0] = F - H0 (row 0: all bits 1..16 set);
        // tens[s>=1] = H0 + rare extras, each a 10-term dot of GL row j (LDS
        // broadcast, quad-uniform j) with crReg (registers).
        #pragma unroll
        for (int r = 0; r < 5; ++r) {
            unsigned ex = msk[r] & exm;    // extras: bits 1..16
            if (r == 0) ex = (q == 0) ? 0u : ex;   // row 0 handled via Fm
            float tn = H0;                 // bit 0 always set for s>=1
            while (ex) {
                int j = __builtin_ctz(ex);
                ex &= ex - 1u;
                const float* gr = &GL[w][j][0];
                float e = 0.f;
                #pragma unroll
                for (int k = 0; k < MN; ++k) e = fmaf(gr[k], crReg[k], e);
                tn += e;
            }
            tens[r] = tn;
        }
        if (q == 0) tens[0] = Fm - H0;
    }

    // dist = sum G * ((1-a)M + a*constC - 2a*tens); lk2 = lkP2b + rm2 (log2 units)
    float val = 0.f;
    #pragma unroll
    for (int r = 0; r < 5; ++r) {
        float cC = npop[r] * p_ + hC2;
        float lk2r = lkP2b[r] + rm2[r];
        float integ = -(0.1f * LN2) * lk2r - alpha * cC - 2.f * alpha * tens[r];
        bool valid = act && (r < 4 || q == 0);
        val += valid ? G[r] * integ : 0.f;
    }
    val = rowsum16(val);
    val = bfly16(val);
    val = bfly32(val);
    if (lane == 0) out[n * T + t] = val;
}

extern "C" void kernel_launch(void* const* d_in, const int* in_sizes, int n_in,
                              void* d_out, int out_size, void* d_ws, size_t ws_size,
                              hipStream_t stream) {
    const float* x      = (const float*)d_in[0];
    const int*   edge   = (const int*)  d_in[1];
    const float* tmpl   = (const float*)d_in[2];
    const float* F2     = (const float*)d_in[3];
    const float* q0     = (const float*)d_in[4];
    const float* alpha0 = (const float*)d_in[5];
    float*       out    = (float*)d_out;

    // ws layout: Mp [N*100] f32 | masks [N*17] u32 | sqF2 [100] f32  (~2.34 MB)
    float*    wsMp    = (float*)d_ws;
    unsigned* wsMask  = (unsigned*)((char*)d_ws + (size_t)NN * T * MN * 4);
    float*    wsSqF2  = (float*)((char*)d_ws + (size_t)NN * T * MN * 4 + (size_t)NN * S * 4);

    hipLaunchKernelGGL(ltfgw_pre, dim3(NN + 1), dim3(320), 0, stream,
                       x, edge, F2, wsMp, wsMask, wsSqF2);
    hipLaunchKernelGGL(ltfgw_wave, dim3(NN * T / WPB), dim3(BLOCK), 0, stream,
                       edge, tmpl, q0, alpha0, wsMp, wsMask, wsSqF2, out);
}

// Round 5
// 221.978 us; speedup vs baseline: 1.3452x; 1.0586x over previous
//
#include <hip/hip_runtime.h>
#include <math.h>

#define NN   5000
#define DEG  16
#define S    17
#define T    10
#define MN   10
#define D    128
#define NOUT 3
#define NSK  5

#define WPB   8            // waves per block (wave-private work; no barrier)
#define BLOCK (WPB * 64)
#define NEG   -3.0e38f
#define LOG2E 1.44269504088896f
#define LN2   0.69314718055995f
#define TINY  1e-30f       // cs floor: keeps inactive-column v_ finite (0*inf=NaN!)

typedef unsigned uint2v __attribute__((ext_vector_type(2)));

__device__ __forceinline__ float fast_rcp(float x) { return __builtin_amdgcn_rcpf(x); }

#if __has_builtin(__builtin_amdgcn_exp2f)
__device__ __forceinline__ float fast_exp2(float x) { return __builtin_amdgcn_exp2f(x); }
#else
__device__ __forceinline__ float fast_exp2(float x) { return __expf(x * LN2); }
#endif

// DPP row_ror:k — pure-VALU cross-lane within each 16-lane row.
template <int CTRL>
__device__ __forceinline__ float dpp_movf(float v) {
    return __int_as_float(__builtin_amdgcn_update_dpp(
        0, __float_as_int(v), CTRL, 0xF, 0xF, true));
}
__device__ __forceinline__ float rowsum16(float v) {
    v += dpp_movf<0x121>(v);
    v += dpp_movf<0x122>(v);
    v += dpp_movf<0x124>(v);
    v += dpp_movf<0x128>(v);
    return v;
}
__device__ __forceinline__ float rowmax16(float v) {
    v = fmaxf(v, dpp_movf<0x121>(v));
    v = fmaxf(v, dpp_movf<0x122>(v));
    v = fmaxf(v, dpp_movf<0x124>(v));
    v = fmaxf(v, dpp_movf<0x128>(v));
    return v;
}

// gfx950 permlane-swap butterflies: v + v[lane^16] / v[lane^32] in pure VALU.
__device__ __forceinline__ float bfly16(float v) {
#if __has_builtin(__builtin_amdgcn_permlane16_swap)
    uint2v r = __builtin_amdgcn_permlane16_swap(__float_as_uint(v), __float_as_uint(v),
                                                false, false);
    return __uint_as_float(r[0]) + __uint_as_float(r[1]);
#else
    return v + __int_as_float(__builtin_amdgcn_ds_swizzle(__float_as_int(v), 0x401F));
#endif
}
__device__ __forceinline__ float bfly32(float v) {
#if __has_builtin(__builtin_amdgcn_permlane32_swap)
    uint2v r = __builtin_amdgcn_permlane32_swap(__float_as_uint(v), __float_as_uint(v),
                                                false, false);
    return __uint_as_float(r[0]) + __uint_as_float(r[1]);
#else
    return v + __shfl_xor(v, 32, 64);
#endif
}

// 10-term dot of an LDS row (16B-aligned, 16-float stride) with a register
// array: 3 vector ds_reads (LDS pipe, co-issues with VALU) + 14 VALU, tree
// depth ~3 — replaces the old 16-step serial DPP rotation (64 VALU, depth 16).
__device__ __forceinline__ float dot10(const float* __restrict__ row,
                                       const float* __restrict__ cr) {
    float4 a = *(const float4*)(row);
    float4 b = *(const float4*)(row + 4);
    float2 c = *(const float2*)(row + 8);
    float e0 = fmaf(cr[1], a.y, cr[0] * a.x);
    float e1 = fmaf(cr[3], a.w, cr[2] * a.z);
    float e2 = fmaf(cr[5], b.y, cr[4] * b.x);
    float e3 = fmaf(cr[7], b.w, cr[6] * b.z);
    float e4 = fmaf(cr[9], c.y, cr[8] * c.x);
    return ((e0 + e1) + (e2 + e3)) + e4;
}

// ---------------- Pre-kernel: batch the per-node redundant work ----------------
// (unchanged) Mp[n,c] = xsq[n] - 2*(x[n].F2f[c]); masks[n][s]; sqF2[100].
__global__ __launch_bounds__(320) void ltfgw_pre(
    const float* __restrict__ x,        // [N, D]
    const int*   __restrict__ edge,     // [2, N*DEG]
    const float* __restrict__ F2,       // [T, MN, D] == [100, D] flat
    float*       __restrict__ wsMp,     // [N, 100]  xsq[n] - 2*dot
    unsigned*    __restrict__ wsMask,   // [N, 17]   adjacency bitmasks
    float*       __restrict__ wsSqF2)   // [100]
{
    const int n   = blockIdx.x;
    const int tid = threadIdx.x;
    const int* dst = edge + NN * DEG;

    if (n == NN) {                       // sqF2[c] = ||F2f[c]||^2
        if (tid < T * MN) {
            const float4* fr = (const float4*)(F2 + (size_t)tid * D);
            float acc = 0.f;
            #pragma unroll 8
            for (int i = 0; i < D / 4; ++i) {
                float4 f = fr[i];
                acc += f.x*f.x + f.y*f.y + f.z*f.z + f.w*f.w;
            }
            wsSqF2[tid] = acc;
        }
        return;
    }

    __shared__ int      loc[S];
    __shared__ int      neigh[S][DEG];
    __shared__ unsigned cm[S];
    __shared__ float    xsq_s;

    if (tid < S) { loc[tid] = (tid == 0) ? n : dst[n * DEG + tid - 1]; cm[tid] = 0u; }
    __syncthreads();

    if (tid < S * DEG) neigh[tid >> 4][tid & 15] = dst[loc[tid >> 4] * DEG + (tid & 15)];
    if (tid < 64) {                      // xsq[n] via wave-0 DPP reduce
        float v0 = x[(size_t)n * D + tid];
        float v1 = x[(size_t)n * D + 64 + tid];
        float pp = v0 * v0 + v1 * v1;
        pp = rowsum16(pp);
        pp += __shfl_xor(pp, 16, 64);
        pp += __shfl_xor(pp, 32, 64);
        if (tid == 0) xsq_s = pp;
    }
    __syncthreads();

    if (tid < S * S) {
        int a = tid / S, b = tid % S;
        int la = loc[a], lb = loc[b];
        bool adj = false;
        #pragma unroll
        for (int k = 0; k < DEG; ++k) adj = adj | (neigh[a][k] == lb) | (neigh[b][k] == la);
        if (a != b && adj) atomicOr(&cm[a], 1u << b);
    }
    __syncthreads();

    if (tid < S) wsMask[n * S + tid] = cm[tid];
    if (tid >= 32 && tid < 32 + T * MN) {  // Mp[n,c] = xsq - 2*(x[n].F2f[c])
        int c = tid - 32;
        const float4* fr = (const float4*)(F2 + (size_t)c * D);
        const float4* xr = (const float4*)(x + (size_t)n * D);
        float dotv = 0.f;
        #pragma unroll 8
        for (int d4 = 0; d4 < D / 4; ++d4) {
            float4 f = fr[d4], xv = xr[d4];
            dotv += f.x*xv.x + f.y*xv.y + f.z*xv.z + f.w*xv.w;
        }
        wsMp[n * (T * MN) + c] = xsq_s - 2.f * dotv;
    }
}

// ---------------- Main: one wave = one (node, template) OT problem ----------------
// Round-13 = round-12 + NaN fix. R12's removal of the act-mask on v_ produced
// cs==0 on inactive columns (all Kt==0 there) -> v_=inf -> next iter
// Kt*v_ = 0*inf = NaN, spread row-wide by the DPP butterfly. Fix: floor the
// column sum with TINY (1e-30) — inactive columns get finite v_ (~1e30),
// Kt*v_ == 0 exactly, ub/G stay exact; active columns perturbed by ~1e-30
// relative. No cndmask back on the 15x serial chain.
// R12 structure kept: dot10() LDS dots replace all 16-deep DPP rotation
// chains; 'act' select off the v-update; tree-summed cs.
// __launch_bounds__: block size ONLY (rounds 2-3: min-waves hint => spills).
__global__ __launch_bounds__(BLOCK) void ltfgw_wave(
    const int*      __restrict__ edge,     // [2, N*DEG]
    const float*    __restrict__ tmpl,     // [T, MN, MN]
    const float*    __restrict__ q0,       // [T, MN]
    const float*    __restrict__ alpha0,   // [1]
    const float*    __restrict__ wsMp,     // [N, 100]
    const unsigned* __restrict__ wsMask,   // [N, 17]
    const float*    __restrict__ wsSqF2,   // [100]
    float*          __restrict__ out)      // [N, T]
{
    const int tid  = threadIdx.x;
    const int w    = tid >> 6;
    const int gid  = blockIdx.x * WPB + w;   // flat (node, template) id
    const int n    = gid / T;
    const int t    = gid - n * T;
    const int lane = tid & 63;
    const int q    = lane >> 4;
    const int m    = lane & 15;
    const bool act = (m < MN);
    const int mc   = act ? m : (MN - 1);

    __shared__ __align__(16) float C2l[WPB][MN][17]; // wave-private; stride 17
    __shared__ __align__(16) float GL[WPB][19][16];  // rows 0-16: G; 17: colG; 18: dump
    __shared__ __align__(16) float QL[WPB][16];      // q-weights (tail zeroed)

    const int* dst = edge + NN * DEG;

    // q = softmax(q0[t]) via DPP row reduction (all lanes)
    float vq = q0[t * MN + mc];
    float zq = act ? vq : NEG;
    float mq = rowmax16(zq);
    float sq = rowsum16(__expf(zq - mq));     // inactive: exp(NEG-mq)=0
    const float qm = __expf(vq - (mq + __logf(sq)));   // valid on act lanes
    if (q == 0) QL[w][m] = act ? qm : 0.f;    // q vector to LDS (tail = 0)
    // C2 = softmax(tmpl, axis=1): active lane m of quad 0 does column m
    if (act && q == 0) {
        float v[MN]; float cmx = NEG;
        #pragma unroll
        for (int i = 0; i < MN; ++i) { v[i] = tmpl[t * MN * MN + i * MN + m]; cmx = fmaxf(cmx, v[i]); }
        float ssum = 0.f;
        #pragma unroll
        for (int i = 0; i < MN; ++i) { v[i] = __expf(v[i] - cmx); ssum += v[i]; }
        float inv = fast_rcp(ssum);
        #pragma unroll
        for (int i = 0; i < MN; ++i) C2l[w][i][m] = v[i] * inv;
    }

    // per-row gathers (L1/L2-resident ws): rows sr[r] = q+4r, clamp 16
    int sr[5];
    #pragma unroll
    for (int r = 0; r < 5; ++r) { int s0 = q + 4 * r; sr[r] = (s0 > 16) ? 16 : s0; }
    unsigned msk[5]; float npop[5]; float Mp[5];
    const int cidx = t * MN + mc;
    #pragma unroll
    for (int r = 0; r < 5; ++r) {
        int lr  = (sr[r] == 0) ? n : dst[n * DEG + sr[r] - 1];
        msk[r]  = wsMask[n * S + sr[r]];
        npop[r] = (float)__popc(msk[r]);
        Mp[r]   = wsMp[lr * (T * MN) + cidx];
    }
    const float sqf2c = wsSqF2[cidx];

    // C2 row mc in registers (stride-17 b32 reads: 10 distinct banks, no
    // conflict; same-wave LDS RAW ordered by compiler lgkmcnt)
    float crReg[MN];
    #pragma unroll
    for (int k = 0; k < MN; ++k) crReg[k] = C2l[w][mc][k];

    // hC2 = sum_k C2[mc][k]^2 q[k]; qC2m = sum_k C2[mc][k] q[k]
    // (q[k] broadcast from LDS; replaces the 16-step rotation pair)
    float hC2 = 0.f, qC2m = 0.f;
    {
        float ql[MN];
        #pragma unroll
        for (int k = 0; k < MN; ++k) ql[k] = QL[w][k];
        #pragma unroll
        for (int k = 0; k < MN; ++k) {
            float cq = crReg[k] * ql[k];
            qC2m += cq;
            hC2  = fmaf(crReg[k], cq, hC2);
        }
    }

    const float alpha = fast_rcp(1.f + __expf(-alpha0[0]));
    const float oma   = 1.f - alpha;
    const float p_    = 1.f / (float)S;
    const float fa42  = 40.f * alpha * LOG2E; // log2K = lkP2 + fa42*tens
    const float qop   = qm * (float)S;        // q/p for folded v-update
    const unsigned exm = act ? 0x1FFFEu : 0u; // extras mask (skip bit 0; gate act)
    const int j16  = (q == 0) ? 16 : 18;      // row-16 G write: q>0 -> dump row

    // lkP2b = log2-domain linear part, pre-shifted by hoisted row stabilizer.
    float lkP2b[5], rm2[5];
    {
        const float nl2e10 = -10.f * LOG2E;
        #pragma unroll
        for (int r = 0; r < 5; ++r) {
            float M_ = Mp[r] + sqf2c;             // xsq + sqf2 - 2*dot
            float cC = npop[r] * p_ + hC2;        // hC1 = popc/S
            float lk2 = nl2e10 * (oma * M_ + 2.f * alpha * cC);
            rm2[r]   = rowmax16(act ? lk2 : NEG) + 14.4f;  // overflow headroom
            lkP2b[r] = lk2 - rm2[r];
        }
    }

    // outer 0 analytic: G0 = p q^T => tens0[r] = p * qC2m * popc(msk[r])
    float tens[5], Kt[5], ub[5], v_, G[5];
    {
        float pq = p_ * qC2m;
        #pragma unroll
        for (int r = 0; r < 5; ++r) tens[r] = pq * npop[r];
    }

    for (int o = 1; o <= NOUT; ++o) {
        // K~ = exp2(lkP2b + fa42*tens)  (rowmax hoisted; Sinkhorn scale-invariant)
        #pragma unroll
        for (int r = 0; r < 5; ++r)
            Kt[r] = act ? fast_exp2(fmaf(fa42, tens[r], lkP2b[r])) : 0.f;
        float Kt4c = (q == 0) ? Kt[4] : 0.f;   // row 16 counted once in cs

        // folded exp-domain Sinkhorn: û = rcp(K~ v); v = (Sq)*rcp(K~^T û)
        // iter 0 peeled (v == 1). cs floored by TINY so inactive columns
        // (all-Kt==0) give finite v_; Kt*v_ stays exactly 0 there.
        #pragma unroll
        for (int r = 0; r < 5; ++r) ub[r] = fast_rcp(rowsum16(Kt[r]));
        {
            float a0 = Kt[0] * ub[0], a1 = Kt[1] * ub[1];
            float a2 = Kt[2] * ub[2], a3 = Kt[3] * ub[3];
            float a4 = fmaf(Kt4c, ub[4], TINY);
            float cs = ((a0 + a1) + (a2 + a3)) + a4;
            cs = bfly16(cs); cs = bfly32(cs);
            v_ = qop * fast_rcp(cs);
        }
        #pragma unroll
        for (int it = 1; it < NSK; ++it) {
            #pragma unroll
            for (int r = 0; r < 5; ++r)
                ub[r] = fast_rcp(rowsum16(Kt[r] * v_));
            float a0 = Kt[0] * ub[0], a1 = Kt[1] * ub[1];
            float a2 = Kt[2] * ub[2], a3 = Kt[3] * ub[3];
            float a4 = fmaf(Kt4c, ub[4], TINY);
            float cs = ((a0 + a1) + (a2 + a3)) + a4;
            cs = bfly16(cs); cs = bfly32(cs);
            v_ = qop * fast_rcp(cs);
        }
        float pv = p_ * v_;
        #pragma unroll
        for (int r = 0; r < 5; ++r) G[r] = Kt[r] * ub[r] * pv;

        // ---- tens = C1*(G*C2^T), star-decomposed; dots via LDS ----
        #pragma unroll
        for (int r = 0; r < 4; ++r) GL[w][q + 4*r][m] = G[r];   // rows 0..15
        GL[w][j16][m] = G[4];                                    // row 16 (q0)
        // colG[k] = sum_j G[j][k] (row 16 counted once); stash in GL row 17
        float cg = (G[0] + G[1]) + (G[2] + G[3]) + ((q == 0) ? G[4] : 0.f);
        cg = bfly16(cg); cg = bfly32(cg);
        if (q == 0) GL[w][17][m] = cg;
        // Fm[m] = sum_k colG[k]*C2[mc][k]; H0[m] = sum_k G[0][k]*C2[mc][k]
        float Fm = dot10(&GL[w][17][0], crReg);
        float H0 = dot10(&GL[w][0][0],  crReg);
        // tens[0] = F - H0 (row 0: all bits 1..16 set);
        // tens[s>=1] = H0 + rare extras (10-term LDS dots, ~0.1 bits/row).
        #pragma unroll
        for (int r = 0; r < 5; ++r) {
            unsigned ex = msk[r] & exm;    // extras: bits 1..16
            if (r == 0) ex = (q == 0) ? 0u : ex;   // row 0 handled via Fm
            float tn = H0;                 // bit 0 always set for s>=1
            while (ex) {
                int j = __builtin_ctz(ex);
                ex &= ex - 1u;
                tn += dot10(&GL[w][j][0], crReg);
            }
            tens[r] = tn;
        }
        if (q == 0) tens[0] = Fm - H0;
    }

    // dist = sum G * ((1-a)M + a*constC - 2a*tens); lk2 = lkP2b + rm2 (log2 units)
    float val = 0.f;
    #pragma unroll
    for (int r = 0; r < 5; ++r) {
        float cC = npop[r] * p_ + hC2;
        float lk2r = lkP2b[r] + rm2[r];
        float integ = -(0.1f * LN2) * lk2r - alpha * cC - 2.f * alpha * tens[r];
        bool valid = act && (r < 4 || q == 0);
        val += valid ? G[r] * integ : 0.f;
    }
    val = rowsum16(val);
    val = bfly16(val);
    val = bfly32(val);
    if (lane == 0) out[n * T + t] = val;
}

extern "C" void kernel_launch(void* const* d_in, const int* in_sizes, int n_in,
                              void* d_out, int out_size, void* d_ws, size_t ws_size,
                              hipStream_t stream) {
    const float* x      = (const float*)d_in[0];
    const int*   edge   = (const int*)  d_in[1];
    const float* tmpl   = (const float*)d_in[2];
    const float* F2     = (const float*)d_in[3];
    const float* q0     = (const float*)d_in[4];
    const float* alpha0 = (const float*)d_in[5];
    float*       out    = (float*)d_out;

    // ws layout: Mp [N*100] f32 | masks [N*17] u32 | sqF2 [100] f32  (~2.34 MB)
    float*    wsMp    = (float*)d_ws;
    unsigned* wsMask  = (unsigned*)((char*)d_ws + (size_t)NN * T * MN * 4);
    float*    wsSqF2  = (float*)((char*)d_ws + (size_t)NN * T * MN * 4 + (size_t)NN * S * 4);

    hipLaunchKernelGGL(ltfgw_pre, dim3(NN + 1), dim3(320), 0, stream,
                       x, edge, F2, wsMp, wsMask, wsSqF2);
    hipLaunchKernelGGL(ltfgw_wave, dim3(NN * T / WPB), dim3(BLOCK), 0, stream,
                       edge, tmpl, q0, alpha0, wsMp, wsMask, wsSqF2, out);
}